// Round 17
// baseline (611.778 us; speedup 1.0000x reference)
//
#include <hip/hip_runtime.h>
#include <cstdint>
#include <cstddef>

#define B_ROWS 16384
#define DIN 784
#define HD 512
#define LD 32

typedef __attribute__((ext_vector_type(8))) short short8;
typedef __attribute__((ext_vector_type(4))) float f32x4;
typedef __attribute__((ext_vector_type(4))) unsigned short us4;

struct I4 { int x, y, z, w; };
__device__ inline int i4get(I4 v, int z) { return z == 0 ? v.x : z == 1 ? v.y : z == 2 ? v.z : v.w; }
__device__ inline int i8get(I4 lo, I4 hi, int z) { return z < 4 ? i4get(lo, z) : i4get(hi, z - 4); }

// ---------------- bf16 helpers (RNE) ----------------
__device__ inline unsigned short f2bf(float v) {
  union { float f; unsigned u; } x; x.f = v;
  unsigned r = x.u + 0x7fffu + ((x.u >> 16) & 1u);
  return (unsigned short)(r >> 16);
}
__device__ inline float bf2f(unsigned short b) {
  union { unsigned u; float f; } x; x.u = ((unsigned)b) << 16;
  return x.f;
}

// ---------------- threefry2x32 (JAX-exact, 20 rounds) ----------------
__host__ __device__ inline void threefry2x32(uint32_t k0, uint32_t k1,
                                             uint32_t x0, uint32_t x1,
                                             uint32_t& o0, uint32_t& o1) {
  uint32_t ks2 = k0 ^ k1 ^ 0x1BD11BDAu;
#define TF_ROT(x, d) (((x) << (d)) | ((x) >> (32 - (d))))
#define TF_R(r) { x0 += x1; x1 = TF_ROT(x1, r); x1 ^= x0; }
  x0 += k0; x1 += k1;
  TF_R(13) TF_R(15) TF_R(26) TF_R(6)
  x0 += k1; x1 += ks2 + 1u;
  TF_R(17) TF_R(29) TF_R(16) TF_R(24)
  x0 += ks2; x1 += k0 + 2u;
  TF_R(13) TF_R(15) TF_R(26) TF_R(6)
  x0 += k0; x1 += k1 + 3u;
  TF_R(17) TF_R(29) TF_R(16) TF_R(24)
  x0 += k1; x1 += ks2 + 4u;
  TF_R(13) TF_R(15) TF_R(26) TF_R(6)
  x0 += ks2; x1 += k0 + 5u;
  o0 = x0; o1 = x1;
#undef TF_R
#undef TF_ROT
}

__device__ inline float erfinv_f(float x) {
  float w = -log1pf(-x * x);
  float p;
  if (w < 5.0f) {
    w -= 2.5f;
    p = 2.81022636e-08f;
    p = fmaf(p, w, 3.43273939e-07f);
    p = fmaf(p, w, -3.5233877e-06f);
    p = fmaf(p, w, -4.39150654e-06f);
    p = fmaf(p, w, 0.00021858087f);
    p = fmaf(p, w, -0.00125372503f);
    p = fmaf(p, w, -0.00417768164f);
    p = fmaf(p, w, 0.246640727f);
    p = fmaf(p, w, 1.50140941f);
  } else {
    w = sqrtf(w) - 3.0f;
    p = -0.000200214257f;
    p = fmaf(p, w, 0.000100950558f);
    p = fmaf(p, w, 0.00134934322f);
    p = fmaf(p, w, -0.00367342844f);
    p = fmaf(p, w, 0.00573950773f);
    p = fmaf(p, w, -0.0076224613f);
    p = fmaf(p, w, 0.00943887047f);
    p = fmaf(p, w, 1.00167406f);
    p = fmaf(p, w, 2.83297682f);
  }
  return p * x;
}

__device__ inline float jax_normal_elem(uint32_t ka, uint32_t kb, uint32_t idx) {
  uint32_t b1, b2;
  threefry2x32(ka, kb, 0u, idx, b1, b2);
  uint32_t bits = b1 ^ b2;
  uint32_t fb = (bits >> 9) | 0x3f800000u;
  float f = __uint_as_float(fb) - 1.0f;
  const float lo = -0.99999994f;
  float u = f * 2.0f + lo;
  u = fmaxf(u, lo);
  return 1.41421356f * erfinv_f(u);
}

// ---------------- weight transpose+convert (tiled, coalesced) ----------------
struct WJob {
  unsigned short pi;
  unsigned src_off, dst_off, start;
  short K, N, Np, Kp;   // src [K][N] f32 -> dst [Np][Kp] bf16 (zero-padded)
};
struct WJobs { WJob j[56]; unsigned total; };

constexpr WJobs make_jobs() {
  WJobs W{};
  int idx = 0; unsigned start = 0; unsigned d = 0;
  auto add = [&](int pi, unsigned so, int K, int N, int Np, int Kp, unsigned doff) {
    W.j[idx].pi = (unsigned short)pi; W.j[idx].src_off = so; W.j[idx].dst_off = doff;
    W.j[idx].start = start; W.j[idx].K = (short)K; W.j[idx].N = (short)N;
    W.j[idx].Np = (short)Np; W.j[idx].Kp = (short)Kp;
    start += (unsigned)(Np * Kp); ++idx;
  };
  add(0, 0, 784, 512, 512, 832, d); d += 512 * 832;   // enc0t padded to K=832
  for (int i = 0; i < 3; ++i) { add(1, i * 262144u, 512, 512, 512, 512, d); d += 262144; }
  for (int k = 0; k < 7; ++k) { add(2, k * 16384u, 512, 32, 32, 512, d);
                                add(3, k * 16384u, 512, 32, 32, 512, d + 16384); d += 32768; }
  for (int i = 0; i < 6; ++i) { add(4, i * 16384u, 32, 512, 512, 32, d); d += 16384; }
  for (int i = 0; i < 6; ++i) { add(5, i * 16384u, 512, 32, 32, 512, d);
                                add(6, i * 16384u, 512, 32, 32, 512, d + 16384); d += 32768; }
  for (int k = 0; k < 3; ++k) { add(7, k * 16384u, 32, 512, 512, 32, d); d += 16384; }
  for (int k = 0; k < 3; ++k) { add(8, k * 262144u, 512, 512, 512, 512, d); d += 262144; }
  for (int k = 0; k < 3; ++k) { add(9, k * 262144u, 512, 512, 512, 512, d); d += 262144; }
  for (int k = 0; k < 3; ++k) { add(10, k * 262144u, 512, 512, 512, 512, d); d += 262144; }
  for (int i = 0; i < 4; ++i) { add(11, i * 16384u, 32, 512, 512, 32, d); d += 16384; }
  for (int i = 0; i < 4; ++i) { add(12, i * 401408u, 512, 784, 896, 512, d); d += 458752; }
  W.total = start;
  return W;
}
__device__ constexpr WJobs g_jobs = make_jobs();

struct TileTable { unsigned ts[57]; };
constexpr TileTable make_tiles() {
  TileTable T{}; WJobs J = make_jobs();
  unsigned acc = 0;
  for (int i = 0; i < 56; ++i) {
    T.ts[i] = acc;
    acc += (unsigned)(J.j[i].Np / 32) * (unsigned)(J.j[i].Kp / 32);
  }
  T.ts[56] = acc;
  return T;
}
__device__ constexpr TileTable g_tiles = make_tiles();

// arena element offsets (mirror of make_jobs; enc0t = 512*832)
#define OFF_ENC0T 0u
#define OFF_ENCT 425984u
#define OFF_DENSE 1212416u
#define OFF_TWH 1441792u
#define OFF_TMS 1540096u
#define OFF_RP1 1736704u
#define OFF_RP2 1785856u
#define OFF_RQ1 2572288u
#define OFF_RQ2 3358720u
#define OFF_DC1 4145152u
#define OFF_DC2 4210688u
#define ARENA_ELEMS 6045696u

struct WSrcs { const float* p[13]; };

__global__ void wconv_k(WSrcs srcs, unsigned short* __restrict__ arena) {
  __shared__ unsigned short tile[32][34];
  unsigned bid = blockIdx.x;
  int jo = 0;
#pragma unroll 1
  while (jo + 1 < 56 && g_tiles.ts[jo + 1] <= bid) ++jo;
  const WJob J = g_jobs.j[jo];
  unsigned t = bid - g_tiles.ts[jo];
  unsigned ktiles = (unsigned)J.Kp / 32u;
  unsigned n0 = (t / ktiles) * 32u, k0 = (t % ktiles) * 32u;
  int ty = threadIdx.x >> 3, tx4 = (threadIdx.x & 7) * 4;
  float v0 = 0, v1 = 0, v2 = 0, v3 = 0;
  int kk = (int)k0 + ty;
  if (kk < J.K) {
    const float* sp = srcs.p[J.pi] + J.src_off + (size_t)kk * J.N + n0 + tx4;
    int nb = (int)(n0 + tx4);
    if (nb + 3 < J.N) {
      float4 v = *reinterpret_cast<const float4*>(sp);
      v0 = v.x; v1 = v.y; v2 = v.z; v3 = v.w;
    } else {
      if (nb + 0 < J.N) v0 = sp[0];
      if (nb + 1 < J.N) v1 = sp[1];
      if (nb + 2 < J.N) v2 = sp[2];
      if (nb + 3 < J.N) v3 = sp[3];
    }
  }
  tile[tx4 + 0][ty] = f2bf(v0);
  tile[tx4 + 1][ty] = f2bf(v1);
  tile[tx4 + 2][ty] = f2bf(v2);
  tile[tx4 + 3][ty] = f2bf(v3);
  __syncthreads();
  us4 w;
  w.x = tile[ty][tx4 + 0]; w.y = tile[ty][tx4 + 1];
  w.z = tile[ty][tx4 + 2]; w.w = tile[ty][tx4 + 3];
  *reinterpret_cast<us4*>(&arena[J.dst_off + (size_t)(n0 + ty) * J.Kp + k0 + tx4]) = w;
}

// x [B][784] f32 -> xb832 [B][832] bf16 zero-padded (GEMM input)
//                -> xb784 [B][784] bf16 (persistent, BCE epilogue)
__global__ void xconv_k(const float* __restrict__ x, unsigned short* __restrict__ xb832,
                        unsigned short* __restrict__ xb784) {
  unsigned g = blockIdx.x * 256u + threadIdx.x;  // B*208
  unsigned r = g / 208u, c4 = g % 208u;
  unsigned c = c4 * 4u;
  float v0 = 0, v1 = 0, v2 = 0, v3 = 0;
  if (c + 3 < 784u) {
    float4 v = *reinterpret_cast<const float4*>(x + (size_t)r * 784u + c);
    v0 = v.x; v1 = v.y; v2 = v.z; v3 = v.w;
  } else {
    if (c + 0 < 784u) v0 = x[(size_t)r * 784u + c + 0];
    if (c + 1 < 784u) v1 = x[(size_t)r * 784u + c + 1];
    if (c + 2 < 784u) v2 = x[(size_t)r * 784u + c + 2];
    if (c + 3 < 784u) v3 = x[(size_t)r * 784u + c + 3];
  }
  us4 w; w.x = f2bf(v0); w.y = f2bf(v1); w.z = f2bf(v2); w.w = f2bf(v3);
  *reinterpret_cast<us4*>(&xb832[(size_t)r * 832u + c]) = w;
  if (c + 3 < 784u)
    *reinterpret_cast<us4*>(&xb784[(size_t)r * 784u + c]) = w;
}

// ---------------- bf16 MFMA GEMM, fused epilogues ----------------------------
// NW waves as 2 x (NW/2); wave tile (BM/2) x (BN/(NW/2)).
// DB=1: single-buffer __syncthreads loop.  DB>=2: DB-deep rotation with counted
// vmcnt (T4) — future tiles' loads stay in flight across raw s_barriers.
// LDS chunk swizzle (BK==32, rule #21 both-sides): stored 16B-chunk p of row R
// holds global chunk p ^ ((R>>1)&3); source pre-swizzled, read XOR-matched.
// z-batching: 8-entry offset tables (I4 pairs), ternary-select decode.
// ACT: 0=none->f32; 1=lrelu->bf16; 3=packed head (mu identity / sig softplus)->f32
//      4=router partial: sum_col lrelu(v+b1)*b2 -> C[row*sC + by]
//      5=BCE partial via softplus identity: x*v - softplus(v) -> C[row*sC + by]
template <int BM, int BN, int BK, int NW, int DB, int ACT, typename OT>
__global__ __launch_bounds__(NW * 64)
void mgemm_k(const unsigned short* __restrict__ A, int sA,
             const unsigned short* __restrict__ Wt,
             const float* __restrict__ b1, const float* __restrict__ b2,
             OT* __restrict__ C, int sC, int Nreal, int K,
             I4 zAo, I4 zAoH, I4 zWo, I4 zWoH, I4 zCo, I4 zCoH,
             int zB1, int zB2,
             const unsigned short* __restrict__ xx) {
  constexpr int WCN = NW / 2;            // wave cols
  constexpr int WN = BN / WCN;
  constexpr int NF = WN / 16;
  constexpr int MR = BM / 2 / 16;
  constexpr int KS = BK / 32;
  constexpr int LPR = BK / 8;
  constexpr int RPC = 64 / LPR;
  constexpr int CA = BM / RPC, CB = BN / RPC;
  constexpr int CAW = (CA >= NW) ? CA / NW : 1;
  constexpr int CBW = (CB >= NW) ? CB / NW : 1;
  constexpr int LPW = CAW + CBW;
  __shared__ unsigned short As[DB][BM][BK];
  __shared__ unsigned short Bs[DB][BN][BK];
  __shared__ float sums[BM][WCN];

  // ---- XCD-aware bijective swizzle (gridDim.x % 8 == 0 for all uses) ----
  int bx, by, bz;
  {
    const int nx = gridDim.x, ny = gridDim.y;
    const int L = blockIdx.x + nx * (blockIdx.y + ny * blockIdx.z);
    const int xw = nx >> 3;
    const int xcd = L & 7, i = L >> 3;
    bx = xcd * xw + i % xw;
    const int rest = i / xw;
    by = rest % ny;
    bz = rest / ny;
  }

  A += i8get(zAo, zAoH, bz);
  Wt += i8get(zWo, zWoH, bz);
  C += i8get(zCo, zCoH, bz);
  b1 += (size_t)bz * zB1;
  if (ACT == 3 || ACT == 4) { if (b2) b2 += (size_t)bz * zB2; }

  const int tid = threadIdx.x;
  const int lane = tid & 63;
  const int wid = tid >> 6;
  const int wr = wid / WCN, wc = wid % WCN;
  const int bm = bx * BM;
  const int bn = by * BN;
  const int lr = lane / LPR;
  // pre-swizzled source chunk (BK==32): chunk (lane&3) ^ ((lane>>3)&3)
  const int lk = (BK == 32) ? (((lane & 3) ^ ((lane >> 3) & 3)) * 8)
                            : ((lane % LPR) * 8);

  auto stage = [&](int buf, int k0) {
#pragma unroll
    for (int cc = 0; cc < CAW; ++cc) {
      int c = wid * CAW + cc;
      if (CAW * NW == CA || c < CA) {
        const unsigned short* g = A + (size_t)(bm + c * RPC + lr) * sA + k0 + lk;
        __builtin_amdgcn_global_load_lds(
            (const __attribute__((address_space(1))) void*)g,
            (__attribute__((address_space(3))) void*)(&As[buf][c * RPC][0]), 16, 0, 0);
      }
    }
#pragma unroll
    for (int cc = 0; cc < CBW; ++cc) {
      int c = wid * CBW + cc;
      if (CBW * NW == CB || c < CB) {
        const unsigned short* g = Wt + (size_t)(bn + c * RPC + lr) * K + k0 + lk;
        __builtin_amdgcn_global_load_lds(
            (const __attribute__((address_space(1))) void*)g,
            (__attribute__((address_space(3))) void*)(&Bs[buf][c * RPC][0]), 16, 0, 0);
      }
    }
  };

  f32x4 acc[MR][NF];
#pragma unroll
  for (int m = 0; m < MR; ++m)
#pragma unroll
    for (int n = 0; n < NF; ++n) acc[m][n] = (f32x4){0.f, 0.f, 0.f, 0.f};

  const int ar = wr * (BM / 2) + (lane & 15);
  // swizzled read chunk (BK==32): position (lane>>4) ^ ((lane>>1)&3)
  const int ac = (BK == 32) ? ((((lane >> 4) ^ ((lane >> 1) & 3)) & 3) * 8)
                            : ((lane >> 4) * 8);
  const int br = wc * WN + (lane & 15);
  const int nt = K / BK;

  auto compute = [&](int buf) {
    short8 aF[MR][KS], bF[NF][KS];
#pragma unroll
    for (int m = 0; m < MR; ++m)
#pragma unroll
      for (int kk = 0; kk < KS; ++kk)
        aF[m][kk] = *reinterpret_cast<const short8*>(&As[buf][ar + m * 16][ac + kk * 32]);
#pragma unroll
    for (int n = 0; n < NF; ++n)
#pragma unroll
      for (int kk = 0; kk < KS; ++kk)
        bF[n][kk] = *reinterpret_cast<const short8*>(&Bs[buf][br + n * 16][ac + kk * 32]);
#pragma unroll
    for (int kk = 0; kk < KS; ++kk)
#pragma unroll
      for (int m = 0; m < MR; ++m)
#pragma unroll
        for (int n = 0; n < NF; ++n)
          acc[m][n] = __builtin_amdgcn_mfma_f32_16x16x32_bf16(aF[m][kk], bF[n][kk], acc[m][n], 0, 0, 0);
  };

  if constexpr (DB >= 2) {
    stage(0, 0);
    if (DB >= 3 && nt > 1) stage(1, BK);
    for (int t = 0; t < nt; ++t) {
      const int pf = t + DB - 1;
      if (pf < nt) stage(pf % DB, pf * BK);
      int ahead = nt - 1 - t; if (ahead > DB - 1) ahead = DB - 1;
      const int w = ahead * LPW;
      if (w >= 16)     asm volatile("s_waitcnt vmcnt(16)" ::: "memory");
      else if (w >= 8) asm volatile("s_waitcnt vmcnt(8)" ::: "memory");
      else if (w == 6) asm volatile("s_waitcnt vmcnt(6)" ::: "memory");
      else if (w == 4) asm volatile("s_waitcnt vmcnt(4)" ::: "memory");
      else if (w == 3) asm volatile("s_waitcnt vmcnt(3)" ::: "memory");
      else if (w == 2) asm volatile("s_waitcnt vmcnt(2)" ::: "memory");
      else             asm volatile("s_waitcnt vmcnt(0)" ::: "memory");
      __builtin_amdgcn_s_barrier();
      asm volatile("" ::: "memory");
      compute(t % DB);
      asm volatile("" ::: "memory");
      __builtin_amdgcn_s_barrier();
      asm volatile("" ::: "memory");
    }
  } else {
    for (int t = 0; t < nt; ++t) {
      stage(0, t * BK);
      __syncthreads();
      compute(0);
      __syncthreads();
    }
  }

  if constexpr (ACT == 4 || ACT == 5) {
    const int row0 = bm + wr * (BM / 2) + (lane >> 4) * 4;
#pragma unroll
    for (int m = 0; m < MR; ++m) {
#pragma unroll
      for (int r = 0; r < 4; ++r) {
        float s = 0.0f;
        int grow = row0 + m * 16 + r;
#pragma unroll
        for (int n = 0; n < NF; ++n) {
          int col = bn + wc * WN + n * 16 + (lane & 15);
          float v = acc[m][n][r];
          if constexpr (ACT == 4) {
            v += b1[col];
            v = (v >= 0.0f) ? v : 0.3f * v;
            s += v * b2[col];
          } else {
            if (col < Nreal) {
              v += b1[col];
              float sp = fmaxf(v, 0.0f) + __logf(1.0f + __expf(-fabsf(v)));
              float xv = bf2f(xx[(size_t)grow * Nreal + col]);
              s += fmaf(xv, v, -sp);
            }
          }
        }
#pragma unroll
        for (int msk = 1; msk < 16; msk <<= 1) s += __shfl_xor(s, msk, 64);
        if ((lane & 15) == 0) sums[wr * (BM / 2) + m * 16 + (lane >> 4) * 4 + r][wc] = s;
      }
    }
    __syncthreads();
    if (tid < BM) {
      float t = 0.0f;
#pragma unroll
      for (int wv = 0; wv < WCN; ++wv) t += sums[tid][wv];
      float* Cf = (float*)C;
      Cf[(size_t)(bm + tid) * sC + by] = t;
    }
  } else {
#pragma unroll
    for (int m = 0; m < MR; ++m) {
      int row = bm + wr * (BM / 2) + m * 16 + (lane >> 4) * 4;
#pragma unroll
      for (int n = 0; n < NF; ++n) {
        int col = bn + wc * WN + n * 16 + (lane & 15);
        if (col < Nreal) {
#pragma unroll
          for (int r = 0; r < 4; ++r) {
            float v = acc[m][n][r];
            if constexpr (ACT == 3) {
              int nl = col >> 6, cin = col & 63;
              if (cin < 32) {
                v += b1[nl * 32 + cin];
              } else {
                v += b2[nl * 32 + (cin - 32)];
                v = fmaxf(v, 0.0f) + log1pf(__expf(-fabsf(v)));
              }
            } else {
              v += b1[col];
              if (ACT == 1) v = (v >= 0.0f) ? v : 0.3f * v;
            }
            size_t oidx = (size_t)(row + r) * sC + col;
            if constexpr (sizeof(OT) == 2) C[oidx] = (OT)f2bf(v);
            else C[oidx] = (OT)v;
          }
        }
      }
    }
  }
}

// ---------------- per-level node kernel: fusion + KL + sample ----------------
struct Keys { uint32_t a[7]; uint32_t b[7]; };

__global__ void node_k(int kstart, Keys keys,
                       const float* __restrict__ musigAll,
                       const float* __restrict__ mupsigAll,
                       const float* __restrict__ probs,
                       unsigned short* __restrict__ zbuf,
                       float* __restrict__ contrib) {
  const int knode = kstart + blockIdx.y;
  const int row = blockIdx.x * 8 + (threadIdx.x >> 5);
  const int j = threadIdx.x & 31;
  const float* mq = musigAll + (size_t)row * 448 + 64 * knode;
  float mqh = mq[j], sqh = mq[32 + j];
  float mu_q, sig_q, mu_p, sig_p;
  if (knode == 0) {
    mu_p = 0.0f; sig_p = 1.0f; mu_q = mqh; sig_q = sqh;
  } else {
    const float* mp = mupsigAll + (size_t)row * 448 + 64 * knode;
    mu_p = mp[j]; sig_p = mp[32 + j];
    sig_q = 1.0f / (1.0f / sqh + 1.0f / sig_p);
    mu_q = sig_q * (mqh / sqh + mu_p / sig_p);
  }
  float vq = sig_q + 1e-7f, vp = sig_p + 1e-7f;
  float dm = mu_q - mu_p;
  float kj = vq / vp + dm * dm / vp - 1.0f + logf(vp / vq);
#pragma unroll
  for (int msk = 1; msk < 32; msk <<= 1) kj += __shfl_xor(kj, msk, 64);
  float e = jax_normal_elem(keys.a[knode], keys.b[knode], (uint32_t)(row * 32 + j));
  zbuf[(size_t)knode * B_ROWS * 32 + (size_t)row * 32 + j] = f2bf(mu_q + sqrtf(vq) * e);
  if (j == 0) {
    float p = (knode == 0) ? 1.0f : probs[(size_t)knode * B_ROWS + row];
    float kn = fminf(fmaxf(p * 0.5f * kj, -1.0f), 1000.0f);
    contrib[(size_t)knode * B_ROWS + row] = kn;
  }
}

// ---------------- per-level routing combine (4 bins/row) ----------------
__global__ void route_k(int kstart, const float* __restrict__ plp,
                        const float* __restrict__ plqp,
                        const float* __restrict__ rpb3, const float* __restrict__ rqb3,
                        float* __restrict__ probs, float* __restrict__ contrib) {
  const int k = kstart + blockIdx.y;
  const int row = blockIdx.x * 256 + threadIdx.x;
  const float* pp = plp + ((size_t)k * B_ROWS + row) * 4;
  const float* pq = plqp + ((size_t)k * B_ROWS + row) * 4;
  float sl = pp[0] + pp[1] + pp[2] + pp[3];
  float sq = pq[0] + pq[1] + pq[2] + pq[3];
  float pl = 1.0f / (1.0f + expf(-(sl + rpb3[k])));
  float plq = 1.0f / (1.0f + expf(-(sq + rqb3[k])));
  float p = (k == 0) ? 1.0f : probs[(size_t)k * B_ROWS + row];
  float kld = plq * logf(1e-7f + plq / (pl + 1e-7f)) +
              (1.0f - plq) * logf(1e-7f + (1.0f - plq) / (1.0f - pl + 1e-7f));
  contrib[(size_t)(7 + k) * B_ROWS + row] = p * kld;
  probs[(size_t)(2 * k + 1) * B_ROWS + row] = p * plq;
  probs[(size_t)(2 * k + 2) * B_ROWS + row] = p * (1.0f - plq);
}

// ---------------- final assembly (pbce: 7 bins/row) ----------------
__global__ void final_k(const float* __restrict__ contrib, const float* __restrict__ probs,
                        const float* __restrict__ pbce, float* __restrict__ out) {
  const int row = blockIdx.x * 256 + threadIdx.x;
  float s = 0.0f;
#pragma unroll
  for (int i = 0; i < 10; ++i) s += contrib[(size_t)i * B_ROWS + row];
#pragma unroll
  for (int l = 0; l < 4; ++l) {
    const float* pb = pbce + ((size_t)l * B_ROWS + row) * 7;
    float bs = 0.0f;
#pragma unroll
    for (int y = 0; y < 7; ++y) bs += pb[y];
    s += probs[(size_t)(3 + l) * B_ROWS + row] * (-bs);
  }
  out[row] = s;
}

extern "C" void kernel_launch(void* const* d_in, const int* in_sizes, int n_in,
                              void* d_out, int out_size, void* d_ws, size_t ws_size,
                              hipStream_t stream) {
  const float* x      = (const float*)d_in[0];
  const float* enc_W0 = (const float*)d_in[1];
  const float* enc_b0 = (const float*)d_in[2];
  const float* enc_W  = (const float*)d_in[3];
  const float* enc_b  = (const float*)d_in[4];
  const float* dWmu   = (const float*)d_in[5];
  const float* dbmu   = (const float*)d_in[6];
  const float* dWsig  = (const float*)d_in[7];
  const float* dbsig  = (const float*)d_in[8];
  const float* tWh    = (const float*)d_in[9];
  const float* tbh    = (const float*)d_in[10];
  const float* tWmu   = (const float*)d_in[11];
  const float* tbmu   = (const float*)d_in[12];
  const float* tWsig  = (const float*)d_in[13];
  const float* tbsig  = (const float*)d_in[14];
  const float* rpW1   = (const float*)d_in[15];
  const float* rpb1   = (const float*)d_in[16];
  const float* rpW2   = (const float*)d_in[17];
  const float* rpb2   = (const float*)d_in[18];
  const float* rpW3   = (const float*)d_in[19];
  const float* rpb3   = (const float*)d_in[20];
  const float* rqW1   = (const float*)d_in[21];
  const float* rqb1   = (const float*)d_in[22];
  const float* rqW2   = (const float*)d_in[23];
  const float* rqb2   = (const float*)d_in[24];
  const float* rqW3   = (const float*)d_in[25];
  const float* rqb3   = (const float*)d_in[26];
  const float* dcW1   = (const float*)d_in[27];
  const float* dcb1   = (const float*)d_in[28];
  const float* dcW2   = (const float*)d_in[29];
  const float* dcb2   = (const float*)d_in[30];
  float* out = (float*)d_out;
  (void)in_sizes; (void)n_in; (void)out_size; (void)ws_size;

  const size_t BR = B_ROWS;
  // ---- bf16 pool ----
  unsigned short* h = (unsigned short*)d_ws;
  unsigned short* encA  = h;                  // BR*512
  unsigned short* encB  = h + BR * 512;       // BR*512
  unsigned short* encC  = h + BR * 1024;      // BR*512
  unsigned short* bufT  = h + BR * 1536;      // BR*1024
  unsigned short* zbuf  = h + BR * 2560;      // BR*224
  unsigned short* xb784 = h + BR * 2784;      // BR*784 (persistent)
  unsigned short* arena = h + BR * 3568;      // ARENA_ELEMS
  size_t ho = BR * 3568 + ARENA_ELEMS;
  // ---- fp32 pool ----
  float* f = (float*)(h + ho);
  float* musigAll  = f;                       // BR*448
  float* mupsigAll = f + BR * 448;            // BR*448
  float* probs     = f + BR * 896;            // BR*7
  float* plp       = f + BR * 903;            // BR*12
  float* plqp      = f + BR * 915;            // BR*12
  float* pbce      = f + BR * 927;            // BR*28
  float* contrib   = f + BR * 955;            // BR*10
  unsigned short* xb832 = (unsigned short*)f; // aliases musigAll region

  const int offA = 0;
  const int offB = (int)(BR * 512);
  const int offC = (int)(BR * 1024);
  const int offT = (int)(BR * 1536);

  Keys keys;
  for (int k = 0; k < 7; ++k) threefry2x32(0u, 1u, 0u, (uint32_t)k, keys.a[k], keys.b[k]);

  const I4 Z0 = {0, 0, 0, 0};
  constexpr TileTable HT = make_tiles();

  // ---- conversions ----
  xconv_k<<<dim3((B_ROWS * 208) / 256), 256, 0, stream>>>(x, xb832, xb784);
  WSrcs srcs;
  srcs.p[0] = enc_W0; srcs.p[1] = enc_W; srcs.p[2] = dWmu; srcs.p[3] = dWsig;
  srcs.p[4] = tWh; srcs.p[5] = tWmu; srcs.p[6] = tWsig;
  srcs.p[7] = rpW1; srcs.p[8] = rpW2; srcs.p[9] = rqW1; srcs.p[10] = rqW2;
  srcs.p[11] = dcW1; srcs.p[12] = dcW2;
  wconv_k<<<dim3(HT.ts[56]), 256, 0, stream>>>(srcs, arena);

// 4-wave, single-buffer, BM=64 (heads / K=32 / small grids)
#define LAUNCH(BN, BK, ACT, OT, A, sA, W, B1, B2, Cc, sC, Nr, K, gy, gz, zA, zW, zC, zb1, zb2, XX) \
  mgemm_k<64, BN, BK, 4, 1, ACT, OT><<<dim3(B_ROWS / 64, gy, gz), 256, 0, stream>>>( \
      A, sA, W, B1, B2, Cc, sC, Nr, K, zA, Z0, zW, Z0, zC, Z0, zb1, zb2, XX)
// 4-wave fat-tile (64x64/wave), 2-deep counted-vmcnt, BM=128 (big K=512+ GEMMs)
#define LAUNCH8(BN, BK, ACT, OT, A, sA, W, B1, B2, Cc, sC, Nr, K, gy, gz, zA, zW, zC, zb1, zb2, XX) \
  mgemm_k<128, BN, BK, 4, 2, ACT, OT><<<dim3(B_ROWS / 128, gy, gz), 256, 0, stream>>>( \
      A, sA, W, B1, B2, Cc, sC, Nr, K, zA, Z0, zW, Z0, zC, Z0, zb1, zb2, XX)

  // ---- encoder chain (d-only work) ----
  LAUNCH8(128, 32, 1, unsigned short, xb832, 832, arena + OFF_ENC0T, enc_b0, nullptr,
          bufT, 512, 512, 832, 4, 1, Z0, Z0, Z0, 0, 0, nullptr);
  LAUNCH8(128, 32, 1, unsigned short, bufT, 512, arena + OFF_ENCT + 0u, enc_b + 0, nullptr,
          encA, 512, 512, 512, 4, 1, Z0, Z0, Z0, 0, 0, nullptr);
  LAUNCH8(128, 32, 1, unsigned short, encA, 512, arena + OFF_ENCT + 262144u, enc_b + 512, nullptr,
          encB, 512, 512, 512, 4, 1, Z0, Z0, Z0, 0, 0, nullptr);
  LAUNCH8(128, 32, 1, unsigned short, encB, 512, arena + OFF_ENCT + 524288u, enc_b + 1024, nullptr,
          encC, 512, 512, 512, 4, 1, Z0, Z0, Z0, 0, 0, nullptr);

  // ---- ALL 7 dense heads in one gz=7 launch (z = node; A = its encoder) ----
  {
    I4 zA  = {offC, offB, offB, offA}, zAH = {offA, offA, offA, 0};
    I4 zW  = {0, 32768, 65536, 98304}, zWH = {131072, 163840, 196608, 0};
    I4 zC  = {0, 64, 128, 192},        zCH = {256, 320, 384, 0};
    mgemm_k<64, 64, 32, 4, 1, 3, float><<<dim3(B_ROWS / 64, 1, 7), 256, 0, stream>>>(
        h, 512, arena + OFF_DENSE, dbmu, dbsig, musigAll, 448, 64, 512,
        zA, zAH, zW, zWH, zC, zCH, 32, 32, nullptr);
  }

  // rq1_k0: encC -> bufT slice 0
  LAUNCH8(128, 32, 1, unsigned short, encC, 512, arena + OFF_RQ1, rqb1, nullptr,
          bufT, 512, 512, 512, 4, 1, Z0, Z0, Z0, 0, 0, nullptr);
  // rq1_k1 -> encA, rq1_k2 -> encC
  {
    I4 zW = {0, 262144, 0, 0}, zC = {offA, offC, 0, 0};
    LAUNCH8(128, 32, 1, unsigned short, encB, 512, arena + OFF_RQ1 + 262144u, rqb1 + 512, nullptr,
            h, 512, 512, 512, 4, 2, Z0, zW, zC, 512, 0, nullptr);
  }
  // plq for all 3 internal nodes (fused rq2 + dot w3): {bufT, encA, encC} -> plqp
  {
    I4 zA = {offT, offA, offC, 0};
    I4 zW = {0, 262144, 524288, 0};
    I4 zC = {0, (int)(BR * 4), (int)(BR * 8), 0};
    LAUNCH8(128, 32, 4, float, h, 512, arena + OFF_RQ2, rqb2, rqW3,
            plqp, 4, 512, 512, 4, 3, zA, zW, zC, 512, 512, nullptr);
  }

  // ---- level 0 ----
  node_k<<<dim3(B_ROWS / 8, 1), 256, 0, stream>>>(0, keys, musigAll, mupsigAll, probs, zbuf, contrib);
  LAUNCH(128, 32, 1, unsigned short, zbuf, 32, arena + OFF_RP1, rpb1, nullptr,
         bufT, 512, 512, 32, 4, 1, Z0, Z0, Z0, 0, 0, nullptr);
  LAUNCH8(128, 32, 4, float, bufT, 512, arena + OFF_RP2, rpb2, rpW3,
          plp, 4, 512, 512, 4, 1, Z0, Z0, Z0, 0, 0, nullptr);
  route_k<<<dim3(B_ROWS / 256, 1), 256, 0, stream>>>(0, plp, plqp, rpb3, rqb3, probs, contrib);

  // ---- level 1 (nodes 1,2) ----
  LAUNCH(128, 32, 1, unsigned short, zbuf, 32, arena + OFF_TWH, tbh, nullptr,
         bufT, 1024, 1024, 32, 8, 1, Z0, Z0, Z0, 0, 0, nullptr);
  {
    I4 zA = {0, 512, 0, 0}, zW = {0, 32768, 0, 0}, zC = {0, 64, 0, 0};
    LAUNCH(64, 32, 3, float, bufT, 1024, arena + OFF_TMS, tbmu, tbsig,
           mupsigAll + 64, 448, 64, 512, 1, 2, zA, zW, zC, 32, 32, nullptr);
  }
  node_k<<<dim3(B_ROWS / 8, 2), 256, 0, stream>>>(1, keys, musigAll, mupsigAll, probs, zbuf, contrib);
  {
    I4 zA = {0, (int)(BR * 32), 0, 0}, zW = {0, 16384, 0, 0}, zC = {offA, offC, 0, 0};
    LAUNCH(128, 32, 1, unsigned short, zbuf + BR * 32, 32, arena + OFF_RP1 + 16384u, rpb1 + 512, nullptr,
           h, 512, 512, 32, 4, 2, zA, zW, zC, 512, 0, nullptr);
    I4 zA2 = {offA, offC, 0, 0}, zW2 = {0, 262144, 0, 0}, zC2 = {0, (int)(BR * 4), 0, 0};
    LAUNCH8(128, 32, 4, float, h, 512, arena + OFF_RP2 + 262144u, rpb2 + 512, rpW3 + 512,
            plp + BR * 4, 4, 512, 512, 4, 2, zA2, zW2, zC2, 512, 512, nullptr);
  }
  route_k<<<dim3(B_ROWS / 256, 2), 256, 0, stream>>>(1, plp, plqp, rpb3, rqb3, probs, contrib);

  // ---- level 2 (nodes 3..6) ----
  {
    I4 zA = {0, (int)(BR * 32), 0, 0};
    I4 zW = {0, 32768, 0, 0};
    I4 zC = {0, (int)(BR * 1024), 0, 0};
    LAUNCH(128, 32, 1, unsigned short, zbuf + BR * 32, 32, arena + OFF_TWH + 32768u, tbh + 1024, nullptr,
           h, 1024, 1024, 32, 8, 2, zA, zW, zC, 1024, 0, nullptr);
    I4 zA2 = {0, 512, (int)(BR * 1024), (int)(BR * 1024 + 512)};
    I4 zW2 = {0, 32768, 65536, 98304};
    I4 zC2 = {0, 64, 128, 192};
    LAUNCH(64, 32, 3, float, h, 1024, arena + OFF_TMS + 65536u, tbmu + 64, tbsig + 64,
           mupsigAll + 192, 448, 64, 512, 1, 4, zA2, zW2, zC2, 32, 32, nullptr);
  }
  node_k<<<dim3(B_ROWS / 8, 4), 256, 0, stream>>>(3, keys, musigAll, mupsigAll, probs, zbuf, contrib);

  // ---- leaves: dc1 (gz=4) + dc2+BCE (gz=4, fat-wave 2-deep) ----
  {
    I4 zA1 = {0, (int)(BR * 32), (int)(BR * 64), (int)(BR * 96)};
    I4 zW1 = {0, 16384, 32768, 49152};
    I4 zC1 = {0, (int)(BR * 512), (int)(BR * 1024), (int)(BR * 1536)};
    LAUNCH(128, 32, 1, unsigned short, zbuf + BR * 96, 32, arena + OFF_DC1, dcb1, nullptr,
           h, 512, 512, 32, 4, 4, zA1, zW1, zC1, 512, 0, nullptr);
    I4 zA2 = {0, (int)(BR * 512), (int)(BR * 1024), (int)(BR * 1536)};
    I4 zW2 = {0, 458752, 917504, 1376256};
    I4 zC2 = {0, (int)(BR * 7), (int)(BR * 14), (int)(BR * 21)};
    LAUNCH8(128, 32, 5, float, h, 512, arena + OFF_DC2, dcb2, nullptr,
            pbce, 7, 784, 512, 7, 4, zA2, zW2, zC2, 784, 0, xb784);
  }

  final_k<<<dim3(B_ROWS / 256), 256, 0, stream>>>(contrib, probs, pbce, out);
#undef LAUNCH
#undef LAUNCH8
}

// Round 18
// 547.451 us; speedup vs baseline: 1.1175x; 1.1175x over previous
//
#include <hip/hip_runtime.h>
#include <cstdint>
#include <cstddef>

#define B_ROWS 16384
#define DIN 784
#define HD 512
#define LD 32

typedef __attribute__((ext_vector_type(8))) short short8;
typedef __attribute__((ext_vector_type(4))) float f32x4;
typedef __attribute__((ext_vector_type(4))) unsigned short us4;

struct I4 { int x, y, z, w; };
__device__ inline int i4get(I4 v, int z) { return z == 0 ? v.x : z == 1 ? v.y : z == 2 ? v.z : v.w; }
__device__ inline int i8get(I4 lo, I4 hi, int z) { return z < 4 ? i4get(lo, z) : i4get(hi, z - 4); }

// ---------------- bf16 helpers (RNE) ----------------
__device__ inline unsigned short f2bf(float v) {
  union { float f; unsigned u; } x; x.f = v;
  unsigned r = x.u + 0x7fffu + ((x.u >> 16) & 1u);
  return (unsigned short)(r >> 16);
}
__device__ inline float bf2f(unsigned short b) {
  union { unsigned u; float f; } x; x.u = ((unsigned)b) << 16;
  return x.f;
}

// ---------------- threefry2x32 (JAX-exact, 20 rounds) ----------------
__host__ __device__ inline void threefry2x32(uint32_t k0, uint32_t k1,
                                             uint32_t x0, uint32_t x1,
                                             uint32_t& o0, uint32_t& o1) {
  uint32_t ks2 = k0 ^ k1 ^ 0x1BD11BDAu;
#define TF_ROT(x, d) (((x) << (d)) | ((x) >> (32 - (d))))
#define TF_R(r) { x0 += x1; x1 = TF_ROT(x1, r); x1 ^= x0; }
  x0 += k0; x1 += k1;
  TF_R(13) TF_R(15) TF_R(26) TF_R(6)
  x0 += k1; x1 += ks2 + 1u;
  TF_R(17) TF_R(29) TF_R(16) TF_R(24)
  x0 += ks2; x1 += k0 + 2u;
  TF_R(13) TF_R(15) TF_R(26) TF_R(6)
  x0 += k0; x1 += k1 + 3u;
  TF_R(17) TF_R(29) TF_R(16) TF_R(24)
  x0 += k1; x1 += ks2 + 4u;
  TF_R(13) TF_R(15) TF_R(26) TF_R(6)
  x0 += ks2; x1 += k0 + 5u;
  o0 = x0; o1 = x1;
#undef TF_R
#undef TF_ROT
}

__device__ inline float erfinv_f(float x) {
  float w = -log1pf(-x * x);
  float p;
  if (w < 5.0f) {
    w -= 2.5f;
    p = 2.81022636e-08f;
    p = fmaf(p, w, 3.43273939e-07f);
    p = fmaf(p, w, -3.5233877e-06f);
    p = fmaf(p, w, -4.39150654e-06f);
    p = fmaf(p, w, 0.00021858087f);
    p = fmaf(p, w, -0.00125372503f);
    p = fmaf(p, w, -0.00417768164f);
    p = fmaf(p, w, 0.246640727f);
    p = fmaf(p, w, 1.50140941f);
  } else {
    w = sqrtf(w) - 3.0f;
    p = -0.000200214257f;
    p = fmaf(p, w, 0.000100950558f);
    p = fmaf(p, w, 0.00134934322f);
    p = fmaf(p, w, -0.00367342844f);
    p = fmaf(p, w, 0.00573950773f);
    p = fmaf(p, w, -0.0076224613f);
    p = fmaf(p, w, 0.00943887047f);
    p = fmaf(p, w, 1.00167406f);
    p = fmaf(p, w, 2.83297682f);
  }
  return p * x;
}

__device__ inline float jax_normal_elem(uint32_t ka, uint32_t kb, uint32_t idx) {
  uint32_t b1, b2;
  threefry2x32(ka, kb, 0u, idx, b1, b2);
  uint32_t bits = b1 ^ b2;
  uint32_t fb = (bits >> 9) | 0x3f800000u;
  float f = __uint_as_float(fb) - 1.0f;
  const float lo = -0.99999994f;
  float u = f * 2.0f + lo;
  u = fmaxf(u, lo);
  return 1.41421356f * erfinv_f(u);
}

// ---------------- weight transpose+convert (tiled, coalesced) ----------------
struct WJob {
  unsigned short pi;
  unsigned src_off, dst_off, start;
  short K, N, Np, Kp;   // src [K][N] f32 -> dst [Np][Kp] bf16 (zero-padded)
};
struct WJobs { WJob j[56]; unsigned total; };

constexpr WJobs make_jobs() {
  WJobs W{};
  int idx = 0; unsigned start = 0; unsigned d = 0;
  auto add = [&](int pi, unsigned so, int K, int N, int Np, int Kp, unsigned doff) {
    W.j[idx].pi = (unsigned short)pi; W.j[idx].src_off = so; W.j[idx].dst_off = doff;
    W.j[idx].start = start; W.j[idx].K = (short)K; W.j[idx].N = (short)N;
    W.j[idx].Np = (short)Np; W.j[idx].Kp = (short)Kp;
    start += (unsigned)(Np * Kp); ++idx;
  };
  add(0, 0, 784, 512, 512, 832, d); d += 512 * 832;   // enc0t padded to K=832
  for (int i = 0; i < 3; ++i) { add(1, i * 262144u, 512, 512, 512, 512, d); d += 262144; }
  for (int k = 0; k < 7; ++k) { add(2, k * 16384u, 512, 32, 32, 512, d);
                                add(3, k * 16384u, 512, 32, 32, 512, d + 16384); d += 32768; }
  for (int i = 0; i < 6; ++i) { add(4, i * 16384u, 32, 512, 512, 32, d); d += 16384; }
  for (int i = 0; i < 6; ++i) { add(5, i * 16384u, 512, 32, 32, 512, d);
                                add(6, i * 16384u, 512, 32, 32, 512, d + 16384); d += 32768; }
  for (int k = 0; k < 3; ++k) { add(7, k * 16384u, 32, 512, 512, 32, d); d += 16384; }
  for (int k = 0; k < 3; ++k) { add(8, k * 262144u, 512, 512, 512, 512, d); d += 262144; }
  for (int k = 0; k < 3; ++k) { add(9, k * 262144u, 512, 512, 512, 512, d); d += 262144; }
  for (int k = 0; k < 3; ++k) { add(10, k * 262144u, 512, 512, 512, 512, d); d += 262144; }
  for (int i = 0; i < 4; ++i) { add(11, i * 16384u, 32, 512, 512, 32, d); d += 16384; }
  for (int i = 0; i < 4; ++i) { add(12, i * 401408u, 512, 784, 896, 512, d); d += 458752; }
  W.total = start;
  return W;
}
__device__ constexpr WJobs g_jobs = make_jobs();

struct TileTable { unsigned ts[57]; };
constexpr TileTable make_tiles() {
  TileTable T{}; WJobs J = make_jobs();
  unsigned acc = 0;
  for (int i = 0; i < 56; ++i) {
    T.ts[i] = acc;
    acc += (unsigned)(J.j[i].Np / 32) * (unsigned)(J.j[i].Kp / 32);
  }
  T.ts[56] = acc;
  return T;
}
__device__ constexpr TileTable g_tiles = make_tiles();

// arena element offsets (mirror of make_jobs; enc0t = 512*832)
#define OFF_ENC0T 0u
#define OFF_ENCT 425984u
#define OFF_DENSE 1212416u
#define OFF_TWH 1441792u
#define OFF_TMS 1540096u
#define OFF_RP1 1736704u
#define OFF_RP2 1785856u
#define OFF_RQ1 2572288u
#define OFF_RQ2 3358720u
#define OFF_DC1 4145152u
#define OFF_DC2 4210688u
#define ARENA_ELEMS 6045696u

struct WSrcs { const float* p[13]; };

__global__ void wconv_k(WSrcs srcs, unsigned short* __restrict__ arena) {
  __shared__ unsigned short tile[32][34];
  unsigned bid = blockIdx.x;
  int jo = 0;
#pragma unroll 1
  while (jo + 1 < 56 && g_tiles.ts[jo + 1] <= bid) ++jo;
  const WJob J = g_jobs.j[jo];
  unsigned t = bid - g_tiles.ts[jo];
  unsigned ktiles = (unsigned)J.Kp / 32u;
  unsigned n0 = (t / ktiles) * 32u, k0 = (t % ktiles) * 32u;
  int ty = threadIdx.x >> 3, tx4 = (threadIdx.x & 7) * 4;
  float v0 = 0, v1 = 0, v2 = 0, v3 = 0;
  int kk = (int)k0 + ty;
  if (kk < J.K) {
    const float* sp = srcs.p[J.pi] + J.src_off + (size_t)kk * J.N + n0 + tx4;
    int nb = (int)(n0 + tx4);
    if (nb + 3 < J.N) {
      float4 v = *reinterpret_cast<const float4*>(sp);
      v0 = v.x; v1 = v.y; v2 = v.z; v3 = v.w;
    } else {
      if (nb + 0 < J.N) v0 = sp[0];
      if (nb + 1 < J.N) v1 = sp[1];
      if (nb + 2 < J.N) v2 = sp[2];
      if (nb + 3 < J.N) v3 = sp[3];
    }
  }
  tile[tx4 + 0][ty] = f2bf(v0);
  tile[tx4 + 1][ty] = f2bf(v1);
  tile[tx4 + 2][ty] = f2bf(v2);
  tile[tx4 + 3][ty] = f2bf(v3);
  __syncthreads();
  us4 w;
  w.x = tile[ty][tx4 + 0]; w.y = tile[ty][tx4 + 1];
  w.z = tile[ty][tx4 + 2]; w.w = tile[ty][tx4 + 3];
  *reinterpret_cast<us4*>(&arena[J.dst_off + (size_t)(n0 + ty) * J.Kp + k0 + tx4]) = w;
}

// x [B][784] f32 -> xb832 [B][832] bf16 zero-padded (GEMM input)
//                -> xb784 [B][784] bf16 (persistent, BCE epilogue)
__global__ void xconv_k(const float* __restrict__ x, unsigned short* __restrict__ xb832,
                        unsigned short* __restrict__ xb784) {
  unsigned g = blockIdx.x * 256u + threadIdx.x;  // B*208
  unsigned r = g / 208u, c4 = g % 208u;
  unsigned c = c4 * 4u;
  float v0 = 0, v1 = 0, v2 = 0, v3 = 0;
  if (c + 3 < 784u) {
    float4 v = *reinterpret_cast<const float4*>(x + (size_t)r * 784u + c);
    v0 = v.x; v1 = v.y; v2 = v.z; v3 = v.w;
  } else {
    if (c + 0 < 784u) v0 = x[(size_t)r * 784u + c + 0];
    if (c + 1 < 784u) v1 = x[(size_t)r * 784u + c + 1];
    if (c + 2 < 784u) v2 = x[(size_t)r * 784u + c + 2];
    if (c + 3 < 784u) v3 = x[(size_t)r * 784u + c + 3];
  }
  us4 w; w.x = f2bf(v0); w.y = f2bf(v1); w.z = f2bf(v2); w.w = f2bf(v3);
  *reinterpret_cast<us4*>(&xb832[(size_t)r * 832u + c]) = w;
  if (c + 3 < 784u)
    *reinterpret_cast<us4*>(&xb784[(size_t)r * 784u + c]) = w;
}

// ---------------- bf16 MFMA GEMM, fused epilogues ----------------------------
// NW waves as 2 x (NW/2); wave tile (BM/2) x (BN/(NW/2)).
// DB=1: single-buffer __syncthreads loop.  DB>=2: DB-deep rotation with counted
// vmcnt (T4) — future tiles' loads stay in flight across raw s_barriers.
// LDS chunk swizzle (BK==32, rule #21 both-sides): stored 16B-chunk p of row R
// holds global chunk p ^ ((R>>1)&3); source pre-swizzled, read XOR-matched.
// z-batching: 8-entry offset tables (I4 pairs), ternary-select decode.
// ACT: 0=none->f32; 1=lrelu->bf16; 3=packed head (mu identity / sig softplus)->f32
//      4=router partial: sum_col lrelu(v+b1)*b2 -> C[row*sC + by]
//      5=BCE partial via softplus identity: x*v - softplus(v) -> C[row*sC + by]
template <int BM, int BN, int BK, int NW, int DB, int ACT, typename OT>
__global__ __launch_bounds__(NW * 64)
void mgemm_k(const unsigned short* __restrict__ A, int sA,
             const unsigned short* __restrict__ Wt,
             const float* __restrict__ b1, const float* __restrict__ b2,
             OT* __restrict__ C, int sC, int Nreal, int K,
             I4 zAo, I4 zAoH, I4 zWo, I4 zWoH, I4 zCo, I4 zCoH,
             int zB1, int zB2,
             const unsigned short* __restrict__ xx) {
  constexpr int WCN = NW / 2;            // wave cols
  constexpr int WN = BN / WCN;
  constexpr int NF = WN / 16;
  constexpr int MR = BM / 2 / 16;
  constexpr int KS = BK / 32;
  constexpr int LPR = BK / 8;
  constexpr int RPC = 64 / LPR;
  constexpr int CA = BM / RPC, CB = BN / RPC;
  constexpr int CAW = (CA >= NW) ? CA / NW : 1;
  constexpr int CBW = (CB >= NW) ? CB / NW : 1;
  constexpr int LPW = CAW + CBW;
  __shared__ unsigned short As[DB][BM][BK];
  __shared__ unsigned short Bs[DB][BN][BK];
  __shared__ float sums[BM][WCN];

  // ---- XCD-aware bijective swizzle (gridDim.x % 8 == 0 for all uses) ----
  int bx, by, bz;
  {
    const int nx = gridDim.x, ny = gridDim.y;
    const int L = blockIdx.x + nx * (blockIdx.y + ny * blockIdx.z);
    const int xw = nx >> 3;
    const int xcd = L & 7, i = L >> 3;
    bx = xcd * xw + i % xw;
    const int rest = i / xw;
    by = rest % ny;
    bz = rest / ny;
  }

  A += i8get(zAo, zAoH, bz);
  Wt += i8get(zWo, zWoH, bz);
  C += i8get(zCo, zCoH, bz);
  b1 += (size_t)bz * zB1;
  if (ACT == 3 || ACT == 4) { if (b2) b2 += (size_t)bz * zB2; }

  const int tid = threadIdx.x;
  const int lane = tid & 63;
  const int wid = tid >> 6;
  const int wr = wid / WCN, wc = wid % WCN;
  const int bm = bx * BM;
  const int bn = by * BN;
  const int lr = lane / LPR;
  // pre-swizzled source chunk (BK==32): chunk (lane&3) ^ ((lane>>3)&3)
  const int lk = (BK == 32) ? (((lane & 3) ^ ((lane >> 3) & 3)) * 8)
                            : ((lane % LPR) * 8);

  auto stage = [&](int buf, int k0) {
#pragma unroll
    for (int cc = 0; cc < CAW; ++cc) {
      int c = wid * CAW + cc;
      if (CAW * NW == CA || c < CA) {
        const unsigned short* g = A + (size_t)(bm + c * RPC + lr) * sA + k0 + lk;
        __builtin_amdgcn_global_load_lds(
            (const __attribute__((address_space(1))) void*)g,
            (__attribute__((address_space(3))) void*)(&As[buf][c * RPC][0]), 16, 0, 0);
      }
    }
#pragma unroll
    for (int cc = 0; cc < CBW; ++cc) {
      int c = wid * CBW + cc;
      if (CBW * NW == CB || c < CB) {
        const unsigned short* g = Wt + (size_t)(bn + c * RPC + lr) * K + k0 + lk;
        __builtin_amdgcn_global_load_lds(
            (const __attribute__((address_space(1))) void*)g,
            (__attribute__((address_space(3))) void*)(&Bs[buf][c * RPC][0]), 16, 0, 0);
      }
    }
  };

  f32x4 acc[MR][NF];
#pragma unroll
  for (int m = 0; m < MR; ++m)
#pragma unroll
    for (int n = 0; n < NF; ++n) acc[m][n] = (f32x4){0.f, 0.f, 0.f, 0.f};

  const int ar = wr * (BM / 2) + (lane & 15);
  // swizzled read chunk (BK==32): position (lane>>4) ^ ((lane>>1)&3)
  const int ac = (BK == 32) ? ((((lane >> 4) ^ ((lane >> 1) & 3)) & 3) * 8)
                            : ((lane >> 4) * 8);
  const int br = wc * WN + (lane & 15);
  const int nt = K / BK;

  auto compute = [&](int buf) {
    short8 aF[MR][KS], bF[NF][KS];
#pragma unroll
    for (int m = 0; m < MR; ++m)
#pragma unroll
      for (int kk = 0; kk < KS; ++kk)
        aF[m][kk] = *reinterpret_cast<const short8*>(&As[buf][ar + m * 16][ac + kk * 32]);
#pragma unroll
    for (int n = 0; n < NF; ++n)
#pragma unroll
      for (int kk = 0; kk < KS; ++kk)
        bF[n][kk] = *reinterpret_cast<const short8*>(&Bs[buf][br + n * 16][ac + kk * 32]);
#pragma unroll
    for (int kk = 0; kk < KS; ++kk)
#pragma unroll
      for (int m = 0; m < MR; ++m)
#pragma unroll
        for (int n = 0; n < NF; ++n)
          acc[m][n] = __builtin_amdgcn_mfma_f32_16x16x32_bf16(aF[m][kk], bF[n][kk], acc[m][n], 0, 0, 0);
  };

  if constexpr (DB >= 2) {
    stage(0, 0);
    if (DB >= 3 && nt > 1) stage(1, BK);
    for (int t = 0; t < nt; ++t) {
      const int pf = t + DB - 1;
      if (pf < nt) stage(pf % DB, pf * BK);
      int ahead = nt - 1 - t; if (ahead > DB - 1) ahead = DB - 1;
      const int w = ahead * LPW;
      if (w >= 8)      asm volatile("s_waitcnt vmcnt(8)" ::: "memory");
      else if (w == 6) asm volatile("s_waitcnt vmcnt(6)" ::: "memory");
      else if (w == 4) asm volatile("s_waitcnt vmcnt(4)" ::: "memory");
      else if (w == 3) asm volatile("s_waitcnt vmcnt(3)" ::: "memory");
      else if (w == 2) asm volatile("s_waitcnt vmcnt(2)" ::: "memory");
      else             asm volatile("s_waitcnt vmcnt(0)" ::: "memory");
      __builtin_amdgcn_s_barrier();
      asm volatile("" ::: "memory");
      compute(t % DB);
      asm volatile("" ::: "memory");
      __builtin_amdgcn_s_barrier();
      asm volatile("" ::: "memory");
    }
  } else {
    for (int t = 0; t < nt; ++t) {
      stage(0, t * BK);
      __syncthreads();
      compute(0);
      __syncthreads();
    }
  }

  if constexpr (ACT == 4 || ACT == 5) {
    const int row0 = bm + wr * (BM / 2) + (lane >> 4) * 4;
#pragma unroll
    for (int m = 0; m < MR; ++m) {
#pragma unroll
      for (int r = 0; r < 4; ++r) {
        float s = 0.0f;
        int grow = row0 + m * 16 + r;
#pragma unroll
        for (int n = 0; n < NF; ++n) {
          int col = bn + wc * WN + n * 16 + (lane & 15);
          float v = acc[m][n][r];
          if constexpr (ACT == 4) {
            v += b1[col];
            v = (v >= 0.0f) ? v : 0.3f * v;
            s += v * b2[col];
          } else {
            if (col < Nreal) {
              v += b1[col];
              float sp = fmaxf(v, 0.0f) + __logf(1.0f + __expf(-fabsf(v)));
              float xv = bf2f(xx[(size_t)grow * Nreal + col]);
              s += fmaf(xv, v, -sp);
            }
          }
        }
#pragma unroll
        for (int msk = 1; msk < 16; msk <<= 1) s += __shfl_xor(s, msk, 64);
        if ((lane & 15) == 0) sums[wr * (BM / 2) + m * 16 + (lane >> 4) * 4 + r][wc] = s;
      }
    }
    __syncthreads();
    if (tid < BM) {
      float t = 0.0f;
#pragma unroll
      for (int wv = 0; wv < WCN; ++wv) t += sums[tid][wv];
      float* Cf = (float*)C;
      Cf[(size_t)(bm + tid) * sC + by] = t;
    }
  } else {
#pragma unroll
    for (int m = 0; m < MR; ++m) {
      int row = bm + wr * (BM / 2) + m * 16 + (lane >> 4) * 4;
#pragma unroll
      for (int n = 0; n < NF; ++n) {
        int col = bn + wc * WN + n * 16 + (lane & 15);
        if (col < Nreal) {
#pragma unroll
          for (int r = 0; r < 4; ++r) {
            float v = acc[m][n][r];
            if constexpr (ACT == 3) {
              int nl = col >> 6, cin = col & 63;
              if (cin < 32) {
                v += b1[nl * 32 + cin];
              } else {
                v += b2[nl * 32 + (cin - 32)];
                v = fmaxf(v, 0.0f) + log1pf(__expf(-fabsf(v)));
              }
            } else {
              v += b1[col];
              if (ACT == 1) v = (v >= 0.0f) ? v : 0.3f * v;
            }
            size_t oidx = (size_t)(row + r) * sC + col;
            if constexpr (sizeof(OT) == 2) C[oidx] = (OT)f2bf(v);
            else C[oidx] = (OT)v;
          }
        }
      }
    }
  }
}

// ---------------- per-level node kernel: fusion + KL + sample ----------------
struct Keys { uint32_t a[7]; uint32_t b[7]; };

__global__ void node_k(int kstart, Keys keys,
                       const float* __restrict__ musigAll,
                       const float* __restrict__ mupsigAll,
                       const float* __restrict__ probs,
                       unsigned short* __restrict__ zbuf,
                       float* __restrict__ contrib) {
  const int knode = kstart + blockIdx.y;
  const int row = blockIdx.x * 8 + (threadIdx.x >> 5);
  const int j = threadIdx.x & 31;
  const float* mq = musigAll + (size_t)row * 448 + 64 * knode;
  float mqh = mq[j], sqh = mq[32 + j];
  float mu_q, sig_q, mu_p, sig_p;
  if (knode == 0) {
    mu_p = 0.0f; sig_p = 1.0f; mu_q = mqh; sig_q = sqh;
  } else {
    const float* mp = mupsigAll + (size_t)row * 448 + 64 * knode;
    mu_p = mp[j]; sig_p = mp[32 + j];
    sig_q = 1.0f / (1.0f / sqh + 1.0f / sig_p);
    mu_q = sig_q * (mqh / sqh + mu_p / sig_p);
  }
  float vq = sig_q + 1e-7f, vp = sig_p + 1e-7f;
  float dm = mu_q - mu_p;
  float kj = vq / vp + dm * dm / vp - 1.0f + logf(vp / vq);
#pragma unroll
  for (int msk = 1; msk < 32; msk <<= 1) kj += __shfl_xor(kj, msk, 64);
  float e = jax_normal_elem(keys.a[knode], keys.b[knode], (uint32_t)(row * 32 + j));
  zbuf[(size_t)knode * B_ROWS * 32 + (size_t)row * 32 + j] = f2bf(mu_q + sqrtf(vq) * e);
  if (j == 0) {
    float p = (knode == 0) ? 1.0f : probs[(size_t)knode * B_ROWS + row];
    float kn = fminf(fmaxf(p * 0.5f * kj, -1.0f), 1000.0f);
    contrib[(size_t)knode * B_ROWS + row] = kn;
  }
}

// ---------------- per-level routing combine (4 bins/row) ----------------
__global__ void route_k(int kstart, const float* __restrict__ plp,
                        const float* __restrict__ plqp,
                        const float* __restrict__ rpb3, const float* __restrict__ rqb3,
                        float* __restrict__ probs, float* __restrict__ contrib) {
  const int k = kstart + blockIdx.y;
  const int row = blockIdx.x * 256 + threadIdx.x;
  const float* pp = plp + ((size_t)k * B_ROWS + row) * 4;
  const float* pq = plqp + ((size_t)k * B_ROWS + row) * 4;
  float sl = pp[0] + pp[1] + pp[2] + pp[3];
  float sq = pq[0] + pq[1] + pq[2] + pq[3];
  float pl = 1.0f / (1.0f + expf(-(sl + rpb3[k])));
  float plq = 1.0f / (1.0f + expf(-(sq + rqb3[k])));
  float p = (k == 0) ? 1.0f : probs[(size_t)k * B_ROWS + row];
  float kld = plq * logf(1e-7f + plq / (pl + 1e-7f)) +
              (1.0f - plq) * logf(1e-7f + (1.0f - plq) / (1.0f - pl + 1e-7f));
  contrib[(size_t)(7 + k) * B_ROWS + row] = p * kld;
  probs[(size_t)(2 * k + 1) * B_ROWS + row] = p * plq;
  probs[(size_t)(2 * k + 2) * B_ROWS + row] = p * (1.0f - plq);
}

// ---------------- final assembly (pbce: 7 bins/row) ----------------
__global__ void final_k(const float* __restrict__ contrib, const float* __restrict__ probs,
                        const float* __restrict__ pbce, float* __restrict__ out) {
  const int row = blockIdx.x * 256 + threadIdx.x;
  float s = 0.0f;
#pragma unroll
  for (int i = 0; i < 10; ++i) s += contrib[(size_t)i * B_ROWS + row];
#pragma unroll
  for (int l = 0; l < 4; ++l) {
    const float* pb = pbce + ((size_t)l * B_ROWS + row) * 7;
    float bs = 0.0f;
#pragma unroll
    for (int y = 0; y < 7; ++y) bs += pb[y];
    s += probs[(size_t)(3 + l) * B_ROWS + row] * (-bs);
  }
  out[row] = s;
}

extern "C" void kernel_launch(void* const* d_in, const int* in_sizes, int n_in,
                              void* d_out, int out_size, void* d_ws, size_t ws_size,
                              hipStream_t stream) {
  const float* x      = (const float*)d_in[0];
  const float* enc_W0 = (const float*)d_in[1];
  const float* enc_b0 = (const float*)d_in[2];
  const float* enc_W  = (const float*)d_in[3];
  const float* enc_b  = (const float*)d_in[4];
  const float* dWmu   = (const float*)d_in[5];
  const float* dbmu   = (const float*)d_in[6];
  const float* dWsig  = (const float*)d_in[7];
  const float* dbsig  = (const float*)d_in[8];
  const float* tWh    = (const float*)d_in[9];
  const float* tbh    = (const float*)d_in[10];
  const float* tWmu   = (const float*)d_in[11];
  const float* tbmu   = (const float*)d_in[12];
  const float* tWsig  = (const float*)d_in[13];
  const float* tbsig  = (const float*)d_in[14];
  const float* rpW1   = (const float*)d_in[15];
  const float* rpb1   = (const float*)d_in[16];
  const float* rpW2   = (const float*)d_in[17];
  const float* rpb2   = (const float*)d_in[18];
  const float* rpW3   = (const float*)d_in[19];
  const float* rpb3   = (const float*)d_in[20];
  const float* rqW1   = (const float*)d_in[21];
  const float* rqb1   = (const float*)d_in[22];
  const float* rqW2   = (const float*)d_in[23];
  const float* rqb2   = (const float*)d_in[24];
  const float* rqW3   = (const float*)d_in[25];
  const float* rqb3   = (const float*)d_in[26];
  const float* dcW1   = (const float*)d_in[27];
  const float* dcb1   = (const float*)d_in[28];
  const float* dcW2   = (const float*)d_in[29];
  const float* dcb2   = (const float*)d_in[30];
  float* out = (float*)d_out;
  (void)in_sizes; (void)n_in; (void)out_size; (void)ws_size;

  const size_t BR = B_ROWS;
  // ---- bf16 pool ----
  unsigned short* h = (unsigned short*)d_ws;
  unsigned short* encA  = h;                  // BR*512
  unsigned short* encB  = h + BR * 512;       // BR*512
  unsigned short* encC  = h + BR * 1024;      // BR*512
  unsigned short* bufT  = h + BR * 1536;      // BR*1024
  unsigned short* zbuf  = h + BR * 2560;      // BR*224
  unsigned short* xb784 = h + BR * 2784;      // BR*784 (persistent)
  unsigned short* arena = h + BR * 3568;      // ARENA_ELEMS
  size_t ho = BR * 3568 + ARENA_ELEMS;
  // ---- fp32 pool ----
  float* f = (float*)(h + ho);
  float* musigAll  = f;                       // BR*448
  float* mupsigAll = f + BR * 448;            // BR*448
  float* probs     = f + BR * 896;            // BR*7
  float* plp       = f + BR * 903;            // BR*12
  float* plqp      = f + BR * 915;            // BR*12
  float* pbce      = f + BR * 927;            // BR*28
  float* contrib   = f + BR * 955;            // BR*10
  unsigned short* xb832 = (unsigned short*)f; // aliases musigAll region

  const int offA = 0;
  const int offB = (int)(BR * 512);
  const int offC = (int)(BR * 1024);
  const int offT = (int)(BR * 1536);

  Keys keys;
  for (int k = 0; k < 7; ++k) threefry2x32(0u, 1u, 0u, (uint32_t)k, keys.a[k], keys.b[k]);

  const I4 Z0 = {0, 0, 0, 0};
  constexpr TileTable HT = make_tiles();

  // ---- conversions ----
  xconv_k<<<dim3((B_ROWS * 208) / 256), 256, 0, stream>>>(x, xb832, xb784);
  WSrcs srcs;
  srcs.p[0] = enc_W0; srcs.p[1] = enc_W; srcs.p[2] = dWmu; srcs.p[3] = dWsig;
  srcs.p[4] = tWh; srcs.p[5] = tWmu; srcs.p[6] = tWsig;
  srcs.p[7] = rpW1; srcs.p[8] = rpW2; srcs.p[9] = rqW1; srcs.p[10] = rqW2;
  srcs.p[11] = dcW1; srcs.p[12] = dcW2;
  wconv_k<<<dim3(HT.ts[56]), 256, 0, stream>>>(srcs, arena);

// 4-wave, single-buffer, BM=64 (heads / K=32 / small grids)
#define LAUNCH(BN, BK, ACT, OT, A, sA, W, B1, B2, Cc, sC, Nr, K, gy, gz, zA, zW, zC, zb1, zb2, XX) \
  mgemm_k<64, BN, BK, 4, 1, ACT, OT><<<dim3(B_ROWS / 64, gy, gz), 256, 0, stream>>>( \
      A, sA, W, B1, B2, Cc, sC, Nr, K, zA, Z0, zW, Z0, zC, Z0, zb1, zb2, XX)
// 8-wave, 2-deep counted-vmcnt, BM=128 (big K=512+ GEMMs)
#define LAUNCH8(BN, BK, ACT, OT, A, sA, W, B1, B2, Cc, sC, Nr, K, gy, gz, zA, zW, zC, zb1, zb2, XX) \
  mgemm_k<128, BN, BK, 8, 2, ACT, OT><<<dim3(B_ROWS / 128, gy, gz), 512, 0, stream>>>( \
      A, sA, W, B1, B2, Cc, sC, Nr, K, zA, Z0, zW, Z0, zC, Z0, zb1, zb2, XX)

  // ---- encoder chain (d-only work) ----
  LAUNCH8(128, 32, 1, unsigned short, xb832, 832, arena + OFF_ENC0T, enc_b0, nullptr,
          bufT, 512, 512, 832, 4, 1, Z0, Z0, Z0, 0, 0, nullptr);
  LAUNCH8(128, 32, 1, unsigned short, bufT, 512, arena + OFF_ENCT + 0u, enc_b + 0, nullptr,
          encA, 512, 512, 512, 4, 1, Z0, Z0, Z0, 0, 0, nullptr);
  LAUNCH8(128, 32, 1, unsigned short, encA, 512, arena + OFF_ENCT + 262144u, enc_b + 512, nullptr,
          encB, 512, 512, 512, 4, 1, Z0, Z0, Z0, 0, 0, nullptr);
  LAUNCH8(128, 32, 1, unsigned short, encB, 512, arena + OFF_ENCT + 524288u, enc_b + 1024, nullptr,
          encC, 512, 512, 512, 4, 1, Z0, Z0, Z0, 0, 0, nullptr);

  // ---- ALL 7 dense heads in one gz=7 launch (z = node; A = its encoder) ----
  {
    I4 zA  = {offC, offB, offB, offA}, zAH = {offA, offA, offA, 0};
    I4 zW  = {0, 32768, 65536, 98304}, zWH = {131072, 163840, 196608, 0};
    I4 zC  = {0, 64, 128, 192},        zCH = {256, 320, 384, 0};
    mgemm_k<64, 64, 32, 4, 1, 3, float><<<dim3(B_ROWS / 64, 1, 7), 256, 0, stream>>>(
        h, 512, arena + OFF_DENSE, dbmu, dbsig, musigAll, 448, 64, 512,
        zA, zAH, zW, zWH, zC, zCH, 32, 32, nullptr);
  }

  // rq1_k0: encC -> bufT slice 0
  LAUNCH8(128, 32, 1, unsigned short, encC, 512, arena + OFF_RQ1, rqb1, nullptr,
          bufT, 512, 512, 512, 4, 1, Z0, Z0, Z0, 0, 0, nullptr);
  // rq1_k1 -> encA, rq1_k2 -> encC
  {
    I4 zW = {0, 262144, 0, 0}, zC = {offA, offC, 0, 0};
    LAUNCH8(128, 32, 1, unsigned short, encB, 512, arena + OFF_RQ1 + 262144u, rqb1 + 512, nullptr,
            h, 512, 512, 512, 4, 2, Z0, zW, zC, 512, 0, nullptr);
  }
  // plq for all 3 internal nodes (fused rq2 + dot w3): {bufT, encA, encC} -> plqp
  {
    I4 zA = {offT, offA, offC, 0};
    I4 zW = {0, 262144, 524288, 0};
    I4 zC = {0, (int)(BR * 4), (int)(BR * 8), 0};
    LAUNCH8(128, 32, 4, float, h, 512, arena + OFF_RQ2, rqb2, rqW3,
            plqp, 4, 512, 512, 4, 3, zA, zW, zC, 512, 512, nullptr);
  }

  // ---- level 0 ----
  node_k<<<dim3(B_ROWS / 8, 1), 256, 0, stream>>>(0, keys, musigAll, mupsigAll, probs, zbuf, contrib);
  LAUNCH(128, 32, 1, unsigned short, zbuf, 32, arena + OFF_RP1, rpb1, nullptr,
         bufT, 512, 512, 32, 4, 1, Z0, Z0, Z0, 0, 0, nullptr);
  LAUNCH8(128, 32, 4, float, bufT, 512, arena + OFF_RP2, rpb2, rpW3,
          plp, 4, 512, 512, 4, 1, Z0, Z0, Z0, 0, 0, nullptr);
  route_k<<<dim3(B_ROWS / 256, 1), 256, 0, stream>>>(0, plp, plqp, rpb3, rqb3, probs, contrib);

  // ---- level 1 (nodes 1,2) ----
  LAUNCH(128, 32, 1, unsigned short, zbuf, 32, arena + OFF_TWH, tbh, nullptr,
         bufT, 1024, 1024, 32, 8, 1, Z0, Z0, Z0, 0, 0, nullptr);
  {
    I4 zA = {0, 512, 0, 0}, zW = {0, 32768, 0, 0}, zC = {0, 64, 0, 0};
    LAUNCH(64, 32, 3, float, bufT, 1024, arena + OFF_TMS, tbmu, tbsig,
           mupsigAll + 64, 448, 64, 512, 1, 2, zA, zW, zC, 32, 32, nullptr);
  }
  node_k<<<dim3(B_ROWS / 8, 2), 256, 0, stream>>>(1, keys, musigAll, mupsigAll, probs, zbuf, contrib);
  {
    I4 zA = {0, (int)(BR * 32), 0, 0}, zW = {0, 16384, 0, 0}, zC = {offA, offC, 0, 0};
    LAUNCH(128, 32, 1, unsigned short, zbuf + BR * 32, 32, arena + OFF_RP1 + 16384u, rpb1 + 512, nullptr,
           h, 512, 512, 32, 4, 2, zA, zW, zC, 512, 0, nullptr);
    I4 zA2 = {offA, offC, 0, 0}, zW2 = {0, 262144, 0, 0}, zC2 = {0, (int)(BR * 4), 0, 0};
    LAUNCH8(128, 32, 4, float, h, 512, arena + OFF_RP2 + 262144u, rpb2 + 512, rpW3 + 512,
            plp + BR * 4, 4, 512, 512, 4, 2, zA2, zW2, zC2, 512, 512, nullptr);
  }
  route_k<<<dim3(B_ROWS / 256, 2), 256, 0, stream>>>(1, plp, plqp, rpb3, rqb3, probs, contrib);

  // ---- level 2 (nodes 3..6) ----
  {
    I4 zA = {0, (int)(BR * 32), 0, 0};
    I4 zW = {0, 32768, 0, 0};
    I4 zC = {0, (int)(BR * 1024), 0, 0};
    LAUNCH(128, 32, 1, unsigned short, zbuf + BR * 32, 32, arena + OFF_TWH + 32768u, tbh + 1024, nullptr,
           h, 1024, 1024, 32, 8, 2, zA, zW, zC, 1024, 0, nullptr);
    I4 zA2 = {0, 512, (int)(BR * 1024), (int)(BR * 1024 + 512)};
    I4 zW2 = {0, 32768, 65536, 98304};
    I4 zC2 = {0, 64, 128, 192};
    LAUNCH(64, 32, 3, float, h, 1024, arena + OFF_TMS + 65536u, tbmu + 64, tbsig + 64,
           mupsigAll + 192, 448, 64, 512, 1, 4, zA2, zW2, zC2, 32, 32, nullptr);
  }
  node_k<<<dim3(B_ROWS / 8, 4), 256, 0, stream>>>(3, keys, musigAll, mupsigAll, probs, zbuf, contrib);

  // ---- leaves: dc1 (gz=4) + dc2+BCE (gz=4, 8-wave 2-deep) ----
  {
    I4 zA1 = {0, (int)(BR * 32), (int)(BR * 64), (int)(BR * 96)};
    I4 zW1 = {0, 16384, 32768, 49152};
    I4 zC1 = {0, (int)(BR * 512), (int)(BR * 1024), (int)(BR * 1536)};
    LAUNCH(128, 32, 1, unsigned short, zbuf + BR * 96, 32, arena + OFF_DC1, dcb1, nullptr,
           h, 512, 512, 32, 4, 4, zA1, zW1, zC1, 512, 0, nullptr);
    I4 zA2 = {0, (int)(BR * 512), (int)(BR * 1024), (int)(BR * 1536)};
    I4 zW2 = {0, 458752, 917504, 1376256};
    I4 zC2 = {0, (int)(BR * 7), (int)(BR * 14), (int)(BR * 21)};
    LAUNCH8(128, 32, 5, float, h, 512, arena + OFF_DC2, dcb2, nullptr,
            pbce, 7, 784, 512, 7, 4, zA2, zW2, zC2, 784, 0, xb784);
  }

  final_k<<<dim3(B_ROWS / 256), 256, 0, stream>>>(contrib, probs, pbce, out);
#undef LAUNCH
#undef LAUNCH8
}